// Round 6
// baseline (542.555 us; speedup 1.0000x reference)
//
#include <hip/hip_runtime.h>
#include <math.h>

// ---------------------------------------------------------------------------
// GATv2 x2 + mean-pool + linear, MI355X.
// R5: ELL fill rebuilt as dst-range-partitioned scan: each block owns ~196
//     dst nodes, streams the whole dst[] (3.2MB, L2-resident broadcast),
//     slots via LDS atomics, writes a private 37.6KB ELL region once.
//     Zero global atomics, no cnt memset, no cross-XCD line ping-pong.
//     (R4's ell_fill: 65us, VALUBusy 0.36%, 50MB writeback from random 4B
//      scatter. This replaces it with ~24us of L2-BW-bound streaming.)
// ---------------------------------------------------------------------------

#define NEG_BIG (-3.0e38f)
#define ELLC    48
#define OVF_CAP 65536
#define FILL_B  256           // blocks in scan_fill; each owns ceil(N/256) dsts

// ---------------- dst-partitioned ELL fill ----------------
__global__ __launch_bounds__(256) void scan_fill_kernel(
    const int* __restrict__ src, const int* __restrict__ dst,
    int* __restrict__ cnt, int* __restrict__ ell,
    int* __restrict__ novf, int* __restrict__ ovf_dst, int* __restrict__ ovf_src,
    int E, int N, int nodes_per_blk) {
    __shared__ int lcnt[256];   // local per-dst counters (nodes_per_blk <= 256)
    int t  = threadIdx.x;
    int d0 = blockIdx.x * nodes_per_blk;
    int d1 = min(N, d0 + nodes_per_blk);
    lcnt[t] = 0;
    __syncthreads();

    const int4* dst4 = (const int4*)dst;
    int nq = E >> 2;                      // E divisible by 4 in practice
    for (int q = t; q < nq; q += 256) {
        int4 dv = dst4[q];
        int e = q << 2;
#pragma unroll
        for (int k = 0; k < 4; ++k) {
            int d = (k == 0) ? dv.x : (k == 1) ? dv.y : (k == 2) ? dv.z : dv.w;
            if (d >= d0 && d < d1) {
                int pos = atomicAdd(&lcnt[d - d0], 1);
                int s   = src[e + k];
                if (pos < ELLC) {
                    ell[d * ELLC + pos] = s;
                } else {
                    int j = atomicAdd(novf, 1);
                    if (j < OVF_CAP) { ovf_dst[j] = d; ovf_src[j] = s; }
                }
            }
        }
    }
    // scalar tail (E % 4)
    for (int e = (nq << 2) + t; e < E; e += 256) {
        int d = dst[e];
        if (d >= d0 && d < d1) {
            int pos = atomicAdd(&lcnt[d - d0], 1);
            int s   = src[e];
            if (pos < ELLC) {
                ell[d * ELLC + pos] = s;
            } else {
                int j = atomicAdd(novf, 1);
                if (j < OVF_CAP) { ovf_dst[j] = d; ovf_src[j] = s; }
            }
        }
    }
    __syncthreads();
    if (d0 + t < d1) cnt[d0 + t] = lcnt[t];
}

// ---------------- dual GEMM: xl = X*Wl + bl, xr = X*Wr + br ----------------
#define GROWS 32
__global__ __launch_bounds__(256) void dual_gemm64_kernel(
    const float* __restrict__ X,
    const float* __restrict__ Wl, const float* __restrict__ bl,
    const float* __restrict__ Wr, const float* __restrict__ br,
    float* __restrict__ xl, float* __restrict__ xr, int n) {
    __shared__ float WlS[4096], WrS[4096], xS[GROWS * 64];
    int t = threadIdx.x;
    for (int i = t; i < 1024; i += 256) {
        ((float4*)WlS)[i] = ((const float4*)Wl)[i];
        ((float4*)WrS)[i] = ((const float4*)Wr)[i];
    }
    int row0 = blockIdx.x * GROWS;
    for (int i = t; i < GROWS * 16; i += 256) {
        int r = row0 + (i >> 4);
        float4 v = make_float4(0.f, 0.f, 0.f, 0.f);
        if (r < n) v = ((const float4*)(X + (size_t)r * 64))[i & 15];
        ((float4*)xS)[i] = v;
    }
    __syncthreads();
    int h  = t & 63;
    int rb = t >> 6;  // 0..3
    float accl[8], accr[8];
#pragma unroll
    for (int i = 0; i < 8; ++i) { accl[i] = 0.f; accr[i] = 0.f; }
    for (int d = 0; d < 64; ++d) {
        float wl = WlS[d * 64 + h];
        float wr = WrS[d * 64 + h];
#pragma unroll
        for (int i = 0; i < 8; ++i) {
            float xv = xS[(rb + 4 * i) * 64 + d];  // wave-uniform broadcast
            accl[i] += xv * wl;
            accr[i] += xv * wr;
        }
    }
    float blv = bl[h], brv = br[h];
#pragma unroll
    for (int i = 0; i < 8; ++i) {
        int r = row0 + rb + 4 * i;
        if (r < n) {
            xl[(size_t)r * 64 + h] = accl[i] + blv;
            xr[(size_t)r * 64 + h] = accr[i] + brv;
        }
    }
}

// ---------------- per-dst GATv2 aggregation (ELL) ----------------
// wave = 4 groups x 16 lanes; group g handles edge p+g; lane l holds feats 4l..4l+3
__global__ __launch_bounds__(256) void gat_aggregate_kernel(
    const float* __restrict__ xl, const float* __restrict__ xr,
    const int* __restrict__ cnt, const int* __restrict__ ell,
    const int* __restrict__ novf, const int* __restrict__ ovf_dst,
    const int* __restrict__ ovf_src,
    const float* __restrict__ att, const float* __restrict__ bias,
    float* __restrict__ out, int n) {
    int wid  = (blockIdx.x * blockDim.x + threadIdx.x) >> 6;
    int lane = threadIdx.x & 63;
    if (wid >= n) return;
    int g = lane >> 4;   // edge slot within wave
    int l = lane & 15;   // feature quad
    int d = wid;

    float4 xr4  = ((const float4*)(xr + (size_t)d * 64))[l];
    float4 att4 = ((const float4*)att)[l];
    int deg_d = cnt[d];
    int beg = d * ELLC;
    int end = beg + min(deg_d, ELLC);

    float  m = NEG_BIG, s = 0.f;
    float4 acc = make_float4(0.f, 0.f, 0.f, 0.f);
    int p = beg;

    // main loop: 8 edges per iteration (2 per group), all active
    for (; p + 8 <= end; p += 8) {
        int i0 = ell[p + g];
        int i1 = ell[p + 4 + g];
        float4 x0 = ((const float4*)(xl + (size_t)i0 * 64))[l];
        float4 x1 = ((const float4*)(xl + (size_t)i1 * 64))[l];
        float z, c0 = 0.f, c1 = 0.f;
        z = x0.x + xr4.x; c0 += ((z > 0.f) ? z : 0.2f * z) * att4.x;
        z = x0.y + xr4.y; c0 += ((z > 0.f) ? z : 0.2f * z) * att4.y;
        z = x0.z + xr4.z; c0 += ((z > 0.f) ? z : 0.2f * z) * att4.z;
        z = x0.w + xr4.w; c0 += ((z > 0.f) ? z : 0.2f * z) * att4.w;
        z = x1.x + xr4.x; c1 += ((z > 0.f) ? z : 0.2f * z) * att4.x;
        z = x1.y + xr4.y; c1 += ((z > 0.f) ? z : 0.2f * z) * att4.y;
        z = x1.z + xr4.z; c1 += ((z > 0.f) ? z : 0.2f * z) * att4.z;
        z = x1.w + xr4.w; c1 += ((z > 0.f) ? z : 0.2f * z) * att4.w;
#pragma unroll
        for (int sh = 8; sh >= 1; sh >>= 1) {  // reduce within 16 lanes
            c0 += __shfl_xor(c0, sh);
            c1 += __shfl_xor(c1, sh);
        }
        float mn = fmaxf(m, fmaxf(c0, c1));
        float ra = __expf(m - mn);
        float p0 = __expf(c0 - mn);
        float p1 = __expf(c1 - mn);
        s = s * ra + p0 + p1;
        acc.x = acc.x * ra + p0 * x0.x + p1 * x1.x;
        acc.y = acc.y * ra + p0 * x0.y + p1 * x1.y;
        acc.z = acc.z * ra + p0 * x0.z + p1 * x1.z;
        acc.w = acc.w * ra + p0 * x0.w + p1 * x1.w;
        m = mn;
    }
    // tail: 4 edges per iteration, masked
    for (; p < end; p += 4) {
        int  e      = p + g;
        bool active = (e < end);
        int  i0     = active ? ell[e] : 0;
        float4 x0 = ((const float4*)(xl + (size_t)i0 * 64))[l];
        float z, c0 = 0.f;
        z = x0.x + xr4.x; c0 += ((z > 0.f) ? z : 0.2f * z) * att4.x;
        z = x0.y + xr4.y; c0 += ((z > 0.f) ? z : 0.2f * z) * att4.y;
        z = x0.z + xr4.z; c0 += ((z > 0.f) ? z : 0.2f * z) * att4.z;
        z = x0.w + xr4.w; c0 += ((z > 0.f) ? z : 0.2f * z) * att4.w;
#pragma unroll
        for (int sh = 8; sh >= 1; sh >>= 1) c0 += __shfl_xor(c0, sh);
        if (!active) c0 = -INFINITY;   // exp(-inf - finite) == 0, no NaN
        float mn = fmaxf(m, c0);       // mn >= m >= NEG_BIG stays finite
        float ra = __expf(m - mn);
        float cb = __expf(c0 - mn);
        s = s * ra + cb;
        acc.x = acc.x * ra + cb * x0.x;
        acc.y = acc.y * ra + cb * x0.y;
        acc.z = acc.z * ra + cb * x0.z;
        acc.w = acc.w * ra + cb * x0.w;
        m = mn;
    }
    // overflow fold (deg > ELLC): scan tiny global list; empty in practice
    if (deg_d > ELLC) {
        int no = min(*novf, OVF_CAP);
        for (int j = g; j < no; j += 4) {
            bool active = (ovf_dst[j] == d);
            int  i0     = active ? ovf_src[j] : 0;
            float4 x0 = ((const float4*)(xl + (size_t)i0 * 64))[l];
            float z, c0 = 0.f;
            z = x0.x + xr4.x; c0 += ((z > 0.f) ? z : 0.2f * z) * att4.x;
            z = x0.y + xr4.y; c0 += ((z > 0.f) ? z : 0.2f * z) * att4.y;
            z = x0.z + xr4.z; c0 += ((z > 0.f) ? z : 0.2f * z) * att4.z;
            z = x0.w + xr4.w; c0 += ((z > 0.f) ? z : 0.2f * z) * att4.w;
#pragma unroll
            for (int sh = 8; sh >= 1; sh >>= 1) c0 += __shfl_xor(c0, sh);
            if (!active) c0 = -INFINITY;
            float mn = fmaxf(m, c0);
            float ra = __expf(m - mn);
            float cb = __expf(c0 - mn);
            s = s * ra + cb;
            acc.x = acc.x * ra + cb * x0.x;
            acc.y = acc.y * ra + cb * x0.y;
            acc.z = acc.z * ra + cb * x0.z;
            acc.w = acc.w * ra + cb * x0.w;
            m = mn;
        }
    }
    // merge the 4 group accumulators (flash-style), xor 16 then xor 32
#pragma unroll
    for (int mask = 16; mask <= 32; mask <<= 1) {
        float mo = __shfl_xor(m, mask);
        float so = __shfl_xor(s, mask);
        float ax = __shfl_xor(acc.x, mask);
        float ay = __shfl_xor(acc.y, mask);
        float az = __shfl_xor(acc.z, mask);
        float aw = __shfl_xor(acc.w, mask);
        float mn = fmaxf(m, mo);
        float ra = __expf(m - mn);
        float rb = __expf(mo - mn);
        s = s * ra + so * rb;
        acc.x = acc.x * ra + ax * rb;
        acc.y = acc.y * ra + ay * rb;
        acc.z = acc.z * ra + az * rb;
        acc.w = acc.w * ra + aw * rb;
        m = mn;
    }
    if (g == 0) {
        float inv = (s > 0.f) ? (1.f / s) : 0.f;  // deg-0 -> 0 (+bias)
        float4 b4 = ((const float4*)bias)[l];
        float4 v;
        v.x = fmaxf(acc.x * inv + b4.x, 0.f);
        v.y = fmaxf(acc.y * inv + b4.y, 0.f);
        v.z = fmaxf(acc.z * inv + b4.z, 0.f);
        v.w = fmaxf(acc.w * inv + b4.w, 0.f);
        ((float4*)(out + (size_t)d * 64))[l] = v;
    }
}

// ---------------- mean pool over sorted batch ----------------
__global__ __launch_bounds__(256) void pool_kernel(
    const float* __restrict__ h, const int* __restrict__ batch,
    float* __restrict__ sums, float* __restrict__ cnts, int n, int nwaves) {
    int wid  = (blockIdx.x * blockDim.x + threadIdx.x) >> 6;
    int lane = threadIdx.x & 63;
    int per   = (n + nwaves - 1) / nwaves;
    int start = wid * per;
    int end   = min(n, start + per);
    if (start >= end) return;
    int cur   = batch[start];
    float acc = 0.f, cnt = 0.f;
    for (int i = start; i < end; ++i) {
        int g = batch[i];   // wave-uniform
        if (g != cur) {
            atomicAdd(&sums[cur * 64 + lane], acc);
            if (lane == 0) atomicAdd(&cnts[cur], cnt);
            acc = 0.f; cnt = 0.f; cur = g;
        }
        acc += h[(size_t)i * 64 + lane];
        cnt += 1.f;
    }
    atomicAdd(&sums[cur * 64 + lane], acc);
    if (lane == 0) atomicAdd(&cnts[cur], cnt);
}

// ---------------- final: out = (sums/cnt) @ lin_w + lin_b ----------------
__global__ __launch_bounds__(256) void final_kernel(
    const float* __restrict__ sums, const float* __restrict__ cnts,
    const float* __restrict__ lin_w, const float* __restrict__ lin_b,
    float* __restrict__ out, int total) {
    int tid = blockIdx.x * blockDim.x + threadIdx.x;
    if (tid >= total) return;
    int g = tid >> 5, o = tid & 31;
    float inv = 1.f / fmaxf(cnts[g], 1.f);
    float a = 0.f;
    for (int h = 0; h < 64; ++h) a += sums[g * 64 + h] * lin_w[h * 32 + o];
    out[tid] = a * inv + lin_b[o];
}

extern "C" void kernel_launch(void* const* d_in, const int* in_sizes, int n_in,
                              void* d_out, int out_size, void* d_ws, size_t ws_size,
                              hipStream_t stream) {
    const float* x     = (const float*)d_in[0];
    const int*   ei    = (const int*)d_in[1];
    const int*   batch = (const int*)d_in[2];
    const float* Wl1   = (const float*)d_in[3];
    const float* bl1   = (const float*)d_in[4];
    const float* Wr1   = (const float*)d_in[5];
    const float* br1   = (const float*)d_in[6];
    const float* att1  = (const float*)d_in[7];
    const float* bias1 = (const float*)d_in[8];
    const float* Wl2   = (const float*)d_in[9];
    const float* bl2   = (const float*)d_in[10];
    const float* Wr2   = (const float*)d_in[11];
    const float* br2   = (const float*)d_in[12];
    const float* att2  = (const float*)d_in[13];
    const float* bias2 = (const float*)d_in[14];
    const float* lin_w = (const float*)d_in[15];
    const float* lin_b = (const float*)d_in[16];
    float* out = (float*)d_out;

    const int N = in_sizes[0] / 64;
    const int E = in_sizes[1] / 2;
    const int G = out_size / 32;
    const int* src = ei;
    const int* dst = ei + E;

    // ---- workspace carve-up (256B-aligned) ----
    char*  ws  = (char*)d_ws;
    size_t off = 0;
    auto alloc = [&](size_t bytes) -> void* {
        void* p = ws + off;
        off += bytes;
        off = (off + 255) & ~(size_t)255;
        return p;
    };
    float* xl      = (float*)alloc((size_t)N * 64 * sizeof(float));
    float* xr      = (float*)alloc((size_t)N * 64 * sizeof(float));
    float* h1      = (float*)alloc((size_t)N * 64 * sizeof(float));  // also h2
    // zeroed region (contiguous): novf, sums, cnts
    int*   novf    = (int*)alloc(256);
    float* sums    = (float*)alloc((size_t)G * 64 * sizeof(float));
    float* cnts    = (float*)alloc((size_t)G * sizeof(float));
    char*  zend    = ws + off;
    int*   cnt     = (int*)alloc((size_t)N * sizeof(int));   // written by scan_fill
    int*   ell     = (int*)alloc((size_t)N * ELLC * sizeof(int));
    int*   ovf_dst = (int*)alloc((size_t)OVF_CAP * sizeof(int));
    int*   ovf_src = (int*)alloc((size_t)OVF_CAP * sizeof(int));

    hipMemsetAsync(novf, 0, (size_t)(zend - (char*)novf), stream);

    int ggrid = (N + GROWS - 1) / GROWS;
    int agrid = (N + 3) / 4;  // 4 waves/block, 1 wave per dst node
    int npb   = (N + FILL_B - 1) / FILL_B;  // nodes per fill block (<=256)

    // ---- ELL build: dst-partitioned full-stream scan, no global atomics ----
    scan_fill_kernel<<<FILL_B, 256, 0, stream>>>(
        src, dst, cnt, ell, novf, ovf_dst, ovf_src, E, N, npb);

    // ---- layer 1 ----
    dual_gemm64_kernel<<<ggrid, 256, 0, stream>>>(x, Wl1, bl1, Wr1, br1, xl, xr, N);
    gat_aggregate_kernel<<<agrid, 256, 0, stream>>>(
        xl, xr, cnt, ell, novf, ovf_dst, ovf_src, att1, bias1, h1, N);

    // ---- layer 2 (h2 aliases h1: gemm2 consumes h1, agg2 overwrites it) ----
    dual_gemm64_kernel<<<ggrid, 256, 0, stream>>>(h1, Wl2, bl2, Wr2, br2, xl, xr, N);
    gat_aggregate_kernel<<<agrid, 256, 0, stream>>>(
        xl, xr, cnt, ell, novf, ovf_dst, ovf_src, att2, bias2, h1, N);

    // ---- pool + final linear ----
    const int NWAVES = 1024;
    pool_kernel<<<256, 256, 0, stream>>>(h1, batch, sums, cnts, N, NWAVES);
    int total = G * 32;
    final_kernel<<<(total + 255) / 256, 256, 0, stream>>>(sums, cnts, lin_w, lin_b, out, total);
}

// Round 7
// 266.816 us; speedup vs baseline: 2.0334x; 2.0334x over previous
//
#include <hip/hip_runtime.h>
#include <math.h>

// ---------------------------------------------------------------------------
// GATv2 x2 + mean-pool + linear, MI355X.
// R6: revert R5's 256x-redundant scan (543us disaster: 12% occupancy, serial).
//     One-pass atomic ELL fill, but XCD-partitioned at redundancy 8:
//     block i -> edge chunk i>>3, dst partition i&7 (= XCD via round-robin).
//     cnt/ELL lines for a partition are touched from ONE XCD -> no cross-XCD
//     ping-pong. Fill fused with gemm1 (fill blocks first, multiple of 8).
// ---------------------------------------------------------------------------

#define NEG_BIG (-3.0e38f)
#define ELLC    48
#define OVF_CAP 65536
#define ECHUNK  2048          // edges per fill block

// ---------------- dual GEMM body: xl = X*Wl + bl, xr = X*Wr + br ----------
#define GROWS 32
__device__ __forceinline__ void dual_gemm_body(
    int bid, int t,
    const float* __restrict__ X,
    const float* __restrict__ Wl, const float* __restrict__ bl,
    const float* __restrict__ Wr, const float* __restrict__ br,
    float* __restrict__ xl, float* __restrict__ xr, int n,
    float* WlS, float* WrS, float* xS) {
    for (int i = t; i < 1024; i += 256) {
        ((float4*)WlS)[i] = ((const float4*)Wl)[i];
        ((float4*)WrS)[i] = ((const float4*)Wr)[i];
    }
    int row0 = bid * GROWS;
    for (int i = t; i < GROWS * 16; i += 256) {
        int r = row0 + (i >> 4);
        float4 v = make_float4(0.f, 0.f, 0.f, 0.f);
        if (r < n) v = ((const float4*)(X + (size_t)r * 64))[i & 15];
        ((float4*)xS)[i] = v;
    }
    __syncthreads();
    int h  = t & 63;
    int rb = t >> 6;  // 0..3
    float accl[8], accr[8];
#pragma unroll
    for (int i = 0; i < 8; ++i) { accl[i] = 0.f; accr[i] = 0.f; }
    for (int d = 0; d < 64; ++d) {
        float wl = WlS[d * 64 + h];
        float wr = WrS[d * 64 + h];
#pragma unroll
        for (int i = 0; i < 8; ++i) {
            float xv = xS[(rb + 4 * i) * 64 + d];  // wave-uniform broadcast
            accl[i] += xv * wl;
            accr[i] += xv * wr;
        }
    }
    float blv = bl[h], brv = br[h];
#pragma unroll
    for (int i = 0; i < 8; ++i) {
        int r = row0 + rb + 4 * i;
        if (r < n) {
            xl[(size_t)r * 64 + h] = accl[i] + blv;
            xr[(size_t)r * 64 + h] = accr[i] + brv;
        }
    }
}

__global__ __launch_bounds__(256) void dual_gemm64_kernel(
    const float* __restrict__ X,
    const float* __restrict__ Wl, const float* __restrict__ bl,
    const float* __restrict__ Wr, const float* __restrict__ br,
    float* __restrict__ xl, float* __restrict__ xr, int n) {
    __shared__ float WlS[4096], WrS[4096], xS[GROWS * 64];
    dual_gemm_body(blockIdx.x, threadIdx.x, X, Wl, bl, Wr, br, xl, xr, n,
                   WlS, WrS, xS);
}

// ---------------- fused: XCD-partitioned ELL fill + layer-1 dual GEMM -----
// blocks [0, fb): fill. block i: edge chunk i>>3, dst partition i&7.
// blocks [fb, fb+ggrid): gemm1.
__global__ __launch_bounds__(256) void fill_gemm_kernel(
    const int* __restrict__ src, const int* __restrict__ dst,
    int* __restrict__ cnt, int* __restrict__ ell,
    int* __restrict__ novf, int* __restrict__ ovf_dst, int* __restrict__ ovf_src,
    int E, int N, int psize, int fb,
    const float* __restrict__ X,
    const float* __restrict__ Wl, const float* __restrict__ bl,
    const float* __restrict__ Wr, const float* __restrict__ br,
    float* __restrict__ xl, float* __restrict__ xr) {
    __shared__ float WlS[4096], WrS[4096], xS[GROWS * 64];
    int b = blockIdx.x;
    if (b >= fb) {
        dual_gemm_body(b - fb, threadIdx.x, X, Wl, bl, Wr, br, xl, xr, N,
                       WlS, WrS, xS);
        return;
    }
    int t     = threadIdx.x;
    int chunk = b >> 3;
    int p     = b & 7;                    // partition == XCD (round-robin)
    int d0    = p * psize;
    int d1    = min(N, d0 + psize);
    int e0    = chunk * ECHUNK;
    int e1    = min(E, e0 + ECHUNK);
    int nq    = (e1 - e0) >> 2;
    const int4* dst4 = (const int4*)(dst + e0);
    const int4* src4 = (const int4*)(src + e0);
    for (int q = t; q < nq; q += 256) {
        int4 dv = dst4[q];
        int4 sv = src4[q];
#pragma unroll
        for (int k = 0; k < 4; ++k) {
            int d = (k == 0) ? dv.x : (k == 1) ? dv.y : (k == 2) ? dv.z : dv.w;
            int s = (k == 0) ? sv.x : (k == 1) ? sv.y : (k == 2) ? sv.z : sv.w;
            if (d >= d0 && d < d1) {
                int pos = atomicAdd(&cnt[d], 1);
                if (pos < ELLC) {
                    ell[d * ELLC + pos] = s;
                } else {  // P(deg>48) ~ 5e-11 per node
                    int j = atomicAdd(novf, 1);
                    if (j < OVF_CAP) { ovf_dst[j] = d; ovf_src[j] = s; }
                }
            }
        }
    }
    // scalar tail (E % 4)
    for (int e = e0 + (nq << 2) + t; e < e1; e += 256) {
        int d = dst[e];
        if (d >= d0 && d < d1) {
            int pos = atomicAdd(&cnt[d], 1);
            int s   = src[e];
            if (pos < ELLC) {
                ell[d * ELLC + pos] = s;
            } else {
                int j = atomicAdd(novf, 1);
                if (j < OVF_CAP) { ovf_dst[j] = d; ovf_src[j] = s; }
            }
        }
    }
}

// ---------------- per-dst GATv2 aggregation (ELL) ----------------
// wave = 4 groups x 16 lanes; group g handles edge p+g; lane l holds feats 4l..4l+3
__global__ __launch_bounds__(256) void gat_aggregate_kernel(
    const float* __restrict__ xl, const float* __restrict__ xr,
    const int* __restrict__ cnt, const int* __restrict__ ell,
    const int* __restrict__ novf, const int* __restrict__ ovf_dst,
    const int* __restrict__ ovf_src,
    const float* __restrict__ att, const float* __restrict__ bias,
    float* __restrict__ out, int n) {
    int wid  = (blockIdx.x * blockDim.x + threadIdx.x) >> 6;
    int lane = threadIdx.x & 63;
    if (wid >= n) return;
    int g = lane >> 4;   // edge slot within wave
    int l = lane & 15;   // feature quad
    int d = wid;

    float4 xr4  = ((const float4*)(xr + (size_t)d * 64))[l];
    float4 att4 = ((const float4*)att)[l];
    int deg_d = cnt[d];
    int beg = d * ELLC;
    int end = beg + min(deg_d, ELLC);

    float  m = NEG_BIG, s = 0.f;
    float4 acc = make_float4(0.f, 0.f, 0.f, 0.f);
    int p = beg;

    // main loop: 8 edges per iteration (2 per group), all active
    for (; p + 8 <= end; p += 8) {
        int i0 = ell[p + g];
        int i1 = ell[p + 4 + g];
        float4 x0 = ((const float4*)(xl + (size_t)i0 * 64))[l];
        float4 x1 = ((const float4*)(xl + (size_t)i1 * 64))[l];
        float z, c0 = 0.f, c1 = 0.f;
        z = x0.x + xr4.x; c0 += ((z > 0.f) ? z : 0.2f * z) * att4.x;
        z = x0.y + xr4.y; c0 += ((z > 0.f) ? z : 0.2f * z) * att4.y;
        z = x0.z + xr4.z; c0 += ((z > 0.f) ? z : 0.2f * z) * att4.z;
        z = x0.w + xr4.w; c0 += ((z > 0.f) ? z : 0.2f * z) * att4.w;
        z = x1.x + xr4.x; c1 += ((z > 0.f) ? z : 0.2f * z) * att4.x;
        z = x1.y + xr4.y; c1 += ((z > 0.f) ? z : 0.2f * z) * att4.y;
        z = x1.z + xr4.z; c1 += ((z > 0.f) ? z : 0.2f * z) * att4.z;
        z = x1.w + xr4.w; c1 += ((z > 0.f) ? z : 0.2f * z) * att4.w;
#pragma unroll
        for (int sh = 8; sh >= 1; sh >>= 1) {  // reduce within 16 lanes
            c0 += __shfl_xor(c0, sh);
            c1 += __shfl_xor(c1, sh);
        }
        float mn = fmaxf(m, fmaxf(c0, c1));
        float ra = __expf(m - mn);
        float p0 = __expf(c0 - mn);
        float p1 = __expf(c1 - mn);
        s = s * ra + p0 + p1;
        acc.x = acc.x * ra + p0 * x0.x + p1 * x1.x;
        acc.y = acc.y * ra + p0 * x0.y + p1 * x1.y;
        acc.z = acc.z * ra + p0 * x0.z + p1 * x1.z;
        acc.w = acc.w * ra + p0 * x0.w + p1 * x1.w;
        m = mn;
    }
    // tail: 4 edges per iteration, masked
    for (; p < end; p += 4) {
        int  e      = p + g;
        bool active = (e < end);
        int  i0     = active ? ell[e] : 0;
        float4 x0 = ((const float4*)(xl + (size_t)i0 * 64))[l];
        float z, c0 = 0.f;
        z = x0.x + xr4.x; c0 += ((z > 0.f) ? z : 0.2f * z) * att4.x;
        z = x0.y + xr4.y; c0 += ((z > 0.f) ? z : 0.2f * z) * att4.y;
        z = x0.z + xr4.z; c0 += ((z > 0.f) ? z : 0.2f * z) * att4.z;
        z = x0.w + xr4.w; c0 += ((z > 0.f) ? z : 0.2f * z) * att4.w;
#pragma unroll
        for (int sh = 8; sh >= 1; sh >>= 1) c0 += __shfl_xor(c0, sh);
        if (!active) c0 = -INFINITY;   // exp(-inf - finite) == 0, no NaN
        float mn = fmaxf(m, c0);       // mn >= m >= NEG_BIG stays finite
        float ra = __expf(m - mn);
        float cb = __expf(c0 - mn);
        s = s * ra + cb;
        acc.x = acc.x * ra + cb * x0.x;
        acc.y = acc.y * ra + cb * x0.y;
        acc.z = acc.z * ra + cb * x0.z;
        acc.w = acc.w * ra + cb * x0.w;
        m = mn;
    }
    // overflow fold (deg > ELLC): scan tiny global list; empty in practice
    if (deg_d > ELLC) {
        int no = min(*novf, OVF_CAP);
        for (int j = g; j < no; j += 4) {
            bool active = (ovf_dst[j] == d);
            int  i0     = active ? ovf_src[j] : 0;
            float4 x0 = ((const float4*)(xl + (size_t)i0 * 64))[l];
            float z, c0 = 0.f;
            z = x0.x + xr4.x; c0 += ((z > 0.f) ? z : 0.2f * z) * att4.x;
            z = x0.y + xr4.y; c0 += ((z > 0.f) ? z : 0.2f * z) * att4.y;
            z = x0.z + xr4.z; c0 += ((z > 0.f) ? z : 0.2f * z) * att4.z;
            z = x0.w + xr4.w; c0 += ((z > 0.f) ? z : 0.2f * z) * att4.w;
#pragma unroll
            for (int sh = 8; sh >= 1; sh >>= 1) c0 += __shfl_xor(c0, sh);
            if (!active) c0 = -INFINITY;
            float mn = fmaxf(m, c0);
            float ra = __expf(m - mn);
            float cb = __expf(c0 - mn);
            s = s * ra + cb;
            acc.x = acc.x * ra + cb * x0.x;
            acc.y = acc.y * ra + cb * x0.y;
            acc.z = acc.z * ra + cb * x0.z;
            acc.w = acc.w * ra + cb * x0.w;
            m = mn;
        }
    }
    // merge the 4 group accumulators (flash-style), xor 16 then xor 32
#pragma unroll
    for (int mask = 16; mask <= 32; mask <<= 1) {
        float mo = __shfl_xor(m, mask);
        float so = __shfl_xor(s, mask);
        float ax = __shfl_xor(acc.x, mask);
        float ay = __shfl_xor(acc.y, mask);
        float az = __shfl_xor(acc.z, mask);
        float aw = __shfl_xor(acc.w, mask);
        float mn = fmaxf(m, mo);
        float ra = __expf(m - mn);
        float rb = __expf(mo - mn);
        s = s * ra + so * rb;
        acc.x = acc.x * ra + ax * rb;
        acc.y = acc.y * ra + ay * rb;
        acc.z = acc.z * ra + az * rb;
        acc.w = acc.w * ra + aw * rb;
        m = mn;
    }
    if (g == 0) {
        float inv = (s > 0.f) ? (1.f / s) : 0.f;  // deg-0 -> 0 (+bias)
        float4 b4 = ((const float4*)bias)[l];
        float4 v;
        v.x = fmaxf(acc.x * inv + b4.x, 0.f);
        v.y = fmaxf(acc.y * inv + b4.y, 0.f);
        v.z = fmaxf(acc.z * inv + b4.z, 0.f);
        v.w = fmaxf(acc.w * inv + b4.w, 0.f);
        ((float4*)(out + (size_t)d * 64))[l] = v;
    }
}

// ---------------- mean pool over sorted batch ----------------
__global__ __launch_bounds__(256) void pool_kernel(
    const float* __restrict__ h, const int* __restrict__ batch,
    float* __restrict__ sums, float* __restrict__ cnts, int n, int nwaves) {
    int wid  = (blockIdx.x * blockDim.x + threadIdx.x) >> 6;
    int lane = threadIdx.x & 63;
    int per   = (n + nwaves - 1) / nwaves;
    int start = wid * per;
    int end   = min(n, start + per);
    if (start >= end) return;
    int cur   = batch[start];
    float acc = 0.f, cnt = 0.f;
    for (int i = start; i < end; ++i) {
        int g = batch[i];   // wave-uniform
        if (g != cur) {
            atomicAdd(&sums[cur * 64 + lane], acc);
            if (lane == 0) atomicAdd(&cnts[cur], cnt);
            acc = 0.f; cnt = 0.f; cur = g;
        }
        acc += h[(size_t)i * 64 + lane];
        cnt += 1.f;
    }
    atomicAdd(&sums[cur * 64 + lane], acc);
    if (lane == 0) atomicAdd(&cnts[cur], cnt);
}

// ---------------- final: out = (sums/cnt) @ lin_w + lin_b ----------------
__global__ __launch_bounds__(256) void final_kernel(
    const float* __restrict__ sums, const float* __restrict__ cnts,
    const float* __restrict__ lin_w, const float* __restrict__ lin_b,
    float* __restrict__ out, int total) {
    int tid = blockIdx.x * blockDim.x + threadIdx.x;
    if (tid >= total) return;
    int g = tid >> 5, o = tid & 31;
    float inv = 1.f / fmaxf(cnts[g], 1.f);
    float a = 0.f;
    for (int h = 0; h < 64; ++h) a += sums[g * 64 + h] * lin_w[h * 32 + o];
    out[tid] = a * inv + lin_b[o];
}

extern "C" void kernel_launch(void* const* d_in, const int* in_sizes, int n_in,
                              void* d_out, int out_size, void* d_ws, size_t ws_size,
                              hipStream_t stream) {
    const float* x     = (const float*)d_in[0];
    const int*   ei    = (const int*)d_in[1];
    const int*   batch = (const int*)d_in[2];
    const float* Wl1   = (const float*)d_in[3];
    const float* bl1   = (const float*)d_in[4];
    const float* Wr1   = (const float*)d_in[5];
    const float* br1   = (const float*)d_in[6];
    const float* att1  = (const float*)d_in[7];
    const float* bias1 = (const float*)d_in[8];
    const float* Wl2   = (const float*)d_in[9];
    const float* bl2   = (const float*)d_in[10];
    const float* Wr2   = (const float*)d_in[11];
    const float* br2   = (const float*)d_in[12];
    const float* att2  = (const float*)d_in[13];
    const float* bias2 = (const float*)d_in[14];
    const float* lin_w = (const float*)d_in[15];
    const float* lin_b = (const float*)d_in[16];
    float* out = (float*)d_out;

    const int N = in_sizes[0] / 64;
    const int E = in_sizes[1] / 2;
    const int G = out_size / 32;
    const int* src = ei;
    const int* dst = ei + E;

    // ---- workspace carve-up (256B-aligned) ----
    char*  ws  = (char*)d_ws;
    size_t off = 0;
    auto alloc = [&](size_t bytes) -> void* {
        void* p = ws + off;
        off += bytes;
        off = (off + 255) & ~(size_t)255;
        return p;
    };
    float* xl      = (float*)alloc((size_t)N * 64 * sizeof(float));
    float* xr      = (float*)alloc((size_t)N * 64 * sizeof(float));
    float* h1      = (float*)alloc((size_t)N * 64 * sizeof(float));  // also h2
    // zeroed region (contiguous): cnt, novf, sums, cnts
    int*   cnt     = (int*)alloc((size_t)N * sizeof(int));
    int*   novf    = (int*)alloc(256);
    float* sums    = (float*)alloc((size_t)G * 64 * sizeof(float));
    float* cnts    = (float*)alloc((size_t)G * sizeof(float));
    char*  zend    = ws + off;
    int*   ell     = (int*)alloc((size_t)N * ELLC * sizeof(int));
    int*   ovf_dst = (int*)alloc((size_t)OVF_CAP * sizeof(int));
    int*   ovf_src = (int*)alloc((size_t)OVF_CAP * sizeof(int));

    hipMemsetAsync(cnt, 0, (size_t)(zend - (char*)cnt), stream);

    int ggrid  = (N + GROWS - 1) / GROWS;
    int agrid  = (N + 3) / 4;                    // 4 waves/block, 1 wave/dst
    int nchunk = (E + ECHUNK - 1) / ECHUNK;
    int fb     = nchunk * 8;                     // fill blocks (multiple of 8)
    int psize  = (N + 7) / 8;                    // dst partition size

    // ---- fused: XCD-partitioned ELL fill + layer-1 dual GEMM ----
    fill_gemm_kernel<<<fb + ggrid, 256, 0, stream>>>(
        src, dst, cnt, ell, novf, ovf_dst, ovf_src, E, N, psize, fb,
        x, Wl1, bl1, Wr1, br1, xl, xr);

    gat_aggregate_kernel<<<agrid, 256, 0, stream>>>(
        xl, xr, cnt, ell, novf, ovf_dst, ovf_src, att1, bias1, h1, N);

    // ---- layer 2 (h2 aliases h1: gemm2 consumes h1, agg2 overwrites it) ----
    dual_gemm64_kernel<<<ggrid, 256, 0, stream>>>(h1, Wl2, bl2, Wr2, br2, xl, xr, N);
    gat_aggregate_kernel<<<agrid, 256, 0, stream>>>(
        xl, xr, cnt, ell, novf, ovf_dst, ovf_src, att2, bias2, h1, N);

    // ---- pool + final linear ----
    const int NWAVES = 1024;
    pool_kernel<<<256, 256, 0, stream>>>(h1, batch, sums, cnts, N, NWAVES);
    int total = G * 32;
    final_kernel<<<(total + 255) / 256, 256, 0, stream>>>(sums, cnts, lin_w, lin_b, out, total);
}

// Round 9
// 264.793 us; speedup vs baseline: 2.0490x; 1.0076x over previous
//
#include <hip/hip_runtime.h>
#include <math.h>

// ---------------------------------------------------------------------------
// GATv2 x2 + mean-pool + linear, MI355X.
// R7/R8: (a) nontemporal src/dst streams in fill (stop evicting dirty ELL
//     lines from XCD L2 -> kill 23MB of rewrite/refetch); (b) aggregate:
//     max-free clamped softmax (scores bounded ~|5| by construction;
//     exp(min(c,30)) is an overflow safety net) + fully-unrolled predicated
//     6x8 slot loop -> ~8 independent gathers in flight per wave.
//     R8 fix: __builtin_nontemporal_load needs a native vector type, not
//     HIP's int4 class -> use ext_vector_type(4).
// ---------------------------------------------------------------------------

#define ELLC    48
#define OVF_CAP 65536
#define ECHUNK  2048          // edges per fill block

typedef int vint4 __attribute__((ext_vector_type(4)));

// ---------------- dual GEMM body: xl = X*Wl + bl, xr = X*Wr + br ----------
#define GROWS 32
__device__ __forceinline__ void dual_gemm_body(
    int bid, int t,
    const float* __restrict__ X,
    const float* __restrict__ Wl, const float* __restrict__ bl,
    const float* __restrict__ Wr, const float* __restrict__ br,
    float* __restrict__ xl, float* __restrict__ xr, int n,
    float* WlS, float* WrS, float* xS) {
    for (int i = t; i < 1024; i += 256) {
        ((float4*)WlS)[i] = ((const float4*)Wl)[i];
        ((float4*)WrS)[i] = ((const float4*)Wr)[i];
    }
    int row0 = bid * GROWS;
    for (int i = t; i < GROWS * 16; i += 256) {
        int r = row0 + (i >> 4);
        float4 v = make_float4(0.f, 0.f, 0.f, 0.f);
        if (r < n) v = ((const float4*)(X + (size_t)r * 64))[i & 15];
        ((float4*)xS)[i] = v;
    }
    __syncthreads();
    int h  = t & 63;
    int rb = t >> 6;  // 0..3
    float accl[8], accr[8];
#pragma unroll
    for (int i = 0; i < 8; ++i) { accl[i] = 0.f; accr[i] = 0.f; }
    for (int d = 0; d < 64; ++d) {
        float wl = WlS[d * 64 + h];
        float wr = WrS[d * 64 + h];
#pragma unroll
        for (int i = 0; i < 8; ++i) {
            float xv = xS[(rb + 4 * i) * 64 + d];  // wave-uniform broadcast
            accl[i] += xv * wl;
            accr[i] += xv * wr;
        }
    }
    float blv = bl[h], brv = br[h];
#pragma unroll
    for (int i = 0; i < 8; ++i) {
        int r = row0 + rb + 4 * i;
        if (r < n) {
            xl[(size_t)r * 64 + h] = accl[i] + blv;
            xr[(size_t)r * 64 + h] = accr[i] + brv;
        }
    }
}

__global__ __launch_bounds__(256) void dual_gemm64_kernel(
    const float* __restrict__ X,
    const float* __restrict__ Wl, const float* __restrict__ bl,
    const float* __restrict__ Wr, const float* __restrict__ br,
    float* __restrict__ xl, float* __restrict__ xr, int n) {
    __shared__ float WlS[4096], WrS[4096], xS[GROWS * 64];
    dual_gemm_body(blockIdx.x, threadIdx.x, X, Wl, bl, Wr, br, xl, xr, n,
                   WlS, WrS, xS);
}

// ---------------- fused: XCD-partitioned ELL fill + layer-1 dual GEMM -----
// blocks [0, fb): fill. block i: edge chunk i>>3, dst partition i&7 (=XCD).
// blocks [fb, fb+ggrid): gemm1.
__global__ __launch_bounds__(256) void fill_gemm_kernel(
    const int* __restrict__ src, const int* __restrict__ dst,
    int* __restrict__ cnt, int* __restrict__ ell,
    int* __restrict__ novf, int* __restrict__ ovf_dst, int* __restrict__ ovf_src,
    int E, int N, int psize, int fb,
    const float* __restrict__ X,
    const float* __restrict__ Wl, const float* __restrict__ bl,
    const float* __restrict__ Wr, const float* __restrict__ br,
    float* __restrict__ xl, float* __restrict__ xr) {
    __shared__ float WlS[4096], WrS[4096], xS[GROWS * 64];
    int b = blockIdx.x;
    if (b >= fb) {
        dual_gemm_body(b - fb, threadIdx.x, X, Wl, bl, Wr, br, xl, xr, N,
                       WlS, WrS, xS);
        return;
    }
    int t     = threadIdx.x;
    int chunk = b >> 3;
    int p     = b & 7;                    // partition == XCD (round-robin)
    int d0    = p * psize;
    int d1    = min(N, d0 + psize);
    int e0    = chunk * ECHUNK;
    int e1    = min(E, e0 + ECHUNK);
    int nq    = (e1 - e0) >> 2;
    const vint4* dst4 = (const vint4*)(dst + e0);
    const vint4* src4 = (const vint4*)(src + e0);
    for (int q = t; q < nq; q += 256) {
        // nontemporal: streaming reads must not evict dirty ELL/cnt lines
        vint4 dv = __builtin_nontemporal_load(&dst4[q]);
        vint4 sv = __builtin_nontemporal_load(&src4[q]);
#pragma unroll
        for (int k = 0; k < 4; ++k) {
            int d = dv[k];
            int s = sv[k];
            if (d >= d0 && d < d1) {
                int pos = atomicAdd(&cnt[d], 1);
                if (pos < ELLC) {
                    ell[d * ELLC + pos] = s;
                } else {  // P(deg>48) ~ 5e-11 per node
                    int j = atomicAdd(novf, 1);
                    if (j < OVF_CAP) { ovf_dst[j] = d; ovf_src[j] = s; }
                }
            }
        }
    }
    // scalar tail (E % 4)
    for (int e = e0 + (nq << 2) + t; e < e1; e += 256) {
        int d = dst[e];
        if (d >= d0 && d < d1) {
            int pos = atomicAdd(&cnt[d], 1);
            int s   = src[e];
            if (pos < ELLC) {
                ell[d * ELLC + pos] = s;
            } else {
                int j = atomicAdd(novf, 1);
                if (j < OVF_CAP) { ovf_dst[j] = d; ovf_src[j] = s; }
            }
        }
    }
}

// ---------------- per-dst GATv2 aggregation (ELL, max-free softmax) -------
// wave = 4 groups x 16 lanes; group g handles slot k*8+g and k*8+4+g;
// lane l holds feats 4l..4l+3. Scores bounded (~|5|); exp(min(c,30)) is a
// pure overflow guard, softmax needs no running max.
__global__ __launch_bounds__(256) void gat_aggregate_kernel(
    const float* __restrict__ xl, const float* __restrict__ xr,
    const int* __restrict__ cnt, const int* __restrict__ ell,
    const int* __restrict__ novf, const int* __restrict__ ovf_dst,
    const int* __restrict__ ovf_src,
    const float* __restrict__ att, const float* __restrict__ bias,
    float* __restrict__ out, int n) {
    int wid  = (blockIdx.x * blockDim.x + threadIdx.x) >> 6;
    int lane = threadIdx.x & 63;
    if (wid >= n) return;
    int g = lane >> 4;   // slot group
    int l = lane & 15;   // feature quad
    int d = wid;

    float4 att4 = ((const float4*)att)[l];
    float4 b4   = ((const float4*)bias)[l];
    int deg_d = cnt[d];
    int nd  = min(deg_d, ELLC);
    int beg = d * ELLC;

    if (deg_d == 0) {   // isolated node: out = relu(bias)
        if (g == 0) {
            float4 v;
            v.x = fmaxf(b4.x, 0.f); v.y = fmaxf(b4.y, 0.f);
            v.z = fmaxf(b4.z, 0.f); v.w = fmaxf(b4.w, 0.f);
            ((float4*)(out + (size_t)d * 64))[l] = v;
        }
        return;
    }

    float4 xr4 = ((const float4*)(xr + (size_t)d * 64))[l];
    int i_first = ell[beg];        // nd >= 1 here
    float  s   = 0.f;
    float4 acc = make_float4(0.f, 0.f, 0.f, 0.f);

#pragma unroll
    for (int k = 0; k < 6; ++k) {          // 6*8 = 48 = ELLC
        if (k * 8 < nd) {                  // wave-uniform guard
            int  sa = k * 8 + g, sb = k * 8 + 4 + g;
            bool aa = sa < nd,   ab = sb < nd;
            int  i0 = aa ? ell[beg + sa] : i_first;
            int  i1 = ab ? ell[beg + sb] : i_first;
            float4 x0 = ((const float4*)(xl + (size_t)i0 * 64))[l];
            float4 x1 = ((const float4*)(xl + (size_t)i1 * 64))[l];
            float z, c0 = 0.f, c1 = 0.f;
            z = x0.x + xr4.x; c0 += ((z > 0.f) ? z : 0.2f * z) * att4.x;
            z = x0.y + xr4.y; c0 += ((z > 0.f) ? z : 0.2f * z) * att4.y;
            z = x0.z + xr4.z; c0 += ((z > 0.f) ? z : 0.2f * z) * att4.z;
            z = x0.w + xr4.w; c0 += ((z > 0.f) ? z : 0.2f * z) * att4.w;
            z = x1.x + xr4.x; c1 += ((z > 0.f) ? z : 0.2f * z) * att4.x;
            z = x1.y + xr4.y; c1 += ((z > 0.f) ? z : 0.2f * z) * att4.y;
            z = x1.z + xr4.z; c1 += ((z > 0.f) ? z : 0.2f * z) * att4.z;
            z = x1.w + xr4.w; c1 += ((z > 0.f) ? z : 0.2f * z) * att4.w;
#pragma unroll
            for (int sh = 8; sh >= 1; sh >>= 1) {  // 16-lane reduce
                c0 += __shfl_xor(c0, sh);
                c1 += __shfl_xor(c1, sh);
            }
            float w0 = aa ? __expf(fminf(c0, 30.f)) : 0.f;
            float w1 = ab ? __expf(fminf(c1, 30.f)) : 0.f;
            s += w0 + w1;
            acc.x += w0 * x0.x + w1 * x1.x;
            acc.y += w0 * x0.y + w1 * x1.y;
            acc.z += w0 * x0.z + w1 * x1.z;
            acc.w += w0 * x0.w + w1 * x1.w;
        }
    }
    // overflow fold (deg > ELLC): scan tiny global list; empty in practice
    if (deg_d > ELLC) {
        int no = min(*novf, OVF_CAP);
        for (int j = g; j < no; j += 4) {
            bool active = (ovf_dst[j] == d);
            int  i0     = active ? ovf_src[j] : i_first;
            float4 x0 = ((const float4*)(xl + (size_t)i0 * 64))[l];
            float z, c0 = 0.f;
            z = x0.x + xr4.x; c0 += ((z > 0.f) ? z : 0.2f * z) * att4.x;
            z = x0.y + xr4.y; c0 += ((z > 0.f) ? z : 0.2f * z) * att4.y;
            z = x0.z + xr4.z; c0 += ((z > 0.f) ? z : 0.2f * z) * att4.z;
            z = x0.w + xr4.w; c0 += ((z > 0.f) ? z : 0.2f * z) * att4.w;
#pragma unroll
            for (int sh = 8; sh >= 1; sh >>= 1) c0 += __shfl_xor(c0, sh);
            float w0 = active ? __expf(fminf(c0, 30.f)) : 0.f;
            s += w0;
            acc.x += w0 * x0.x;
            acc.y += w0 * x0.y;
            acc.z += w0 * x0.z;
            acc.w += w0 * x0.w;
        }
    }
    // merge the 4 group partial sums (plain adds), xor 16 then xor 32
#pragma unroll
    for (int mask = 16; mask <= 32; mask <<= 1) {
        s     += __shfl_xor(s, mask);
        acc.x += __shfl_xor(acc.x, mask);
        acc.y += __shfl_xor(acc.y, mask);
        acc.z += __shfl_xor(acc.z, mask);
        acc.w += __shfl_xor(acc.w, mask);
    }
    if (g == 0) {
        float inv = (s > 0.f) ? (1.f / s) : 0.f;
        float4 v;
        v.x = fmaxf(acc.x * inv + b4.x, 0.f);
        v.y = fmaxf(acc.y * inv + b4.y, 0.f);
        v.z = fmaxf(acc.z * inv + b4.z, 0.f);
        v.w = fmaxf(acc.w * inv + b4.w, 0.f);
        ((float4*)(out + (size_t)d * 64))[l] = v;
    }
}

// ---------------- mean pool over sorted batch ----------------
__global__ __launch_bounds__(256) void pool_kernel(
    const float* __restrict__ h, const int* __restrict__ batch,
    float* __restrict__ sums, float* __restrict__ cnts, int n, int nwaves) {
    int wid  = (blockIdx.x * blockDim.x + threadIdx.x) >> 6;
    int lane = threadIdx.x & 63;
    int per   = (n + nwaves - 1) / nwaves;
    int start = wid * per;
    int end   = min(n, start + per);
    if (start >= end) return;
    int cur   = batch[start];
    float acc = 0.f, cnt = 0.f;
    for (int i = start; i < end; ++i) {
        int g = batch[i];   // wave-uniform
        if (g != cur) {
            atomicAdd(&sums[cur * 64 + lane], acc);
            if (lane == 0) atomicAdd(&cnts[cur], cnt);
            acc = 0.f; cnt = 0.f; cur = g;
        }
        acc += h[(size_t)i * 64 + lane];
        cnt += 1.f;
    }
    atomicAdd(&sums[cur * 64 + lane], acc);
    if (lane == 0) atomicAdd(&cnts[cur], cnt);
}

// ---------------- final: out = (sums/cnt) @ lin_w + lin_b ----------------
__global__ __launch_bounds__(256) void final_kernel(
    const float* __restrict__ sums, const float* __restrict__ cnts,
    const float* __restrict__ lin_w, const float* __restrict__ lin_b,
    float* __restrict__ out, int total) {
    int tid = blockIdx.x * blockDim.x + threadIdx.x;
    if (tid >= total) return;
    int g = tid >> 5, o = tid & 31;
    float inv = 1.f / fmaxf(cnts[g], 1.f);
    float a = 0.f;
    for (int h = 0; h < 64; ++h) a += sums[g * 64 + h] * lin_w[h * 32 + o];
    out[tid] = a * inv + lin_b[o];
}

extern "C" void kernel_launch(void* const* d_in, const int* in_sizes, int n_in,
                              void* d_out, int out_size, void* d_ws, size_t ws_size,
                              hipStream_t stream) {
    const float* x     = (const float*)d_in[0];
    const int*   ei    = (const int*)d_in[1];
    const int*   batch = (const int*)d_in[2];
    const float* Wl1   = (const float*)d_in[3];
    const float* bl1   = (const float*)d_in[4];
    const float* Wr1   = (const float*)d_in[5];
    const float* br1   = (const float*)d_in[6];
    const float* att1  = (const float*)d_in[7];
    const float* bias1 = (const float*)d_in[8];
    const float* Wl2   = (const float*)d_in[9];
    const float* bl2   = (const float*)d_in[10];
    const float* Wr2   = (const float*)d_in[11];
    const float* br2   = (const float*)d_in[12];
    const float* att2  = (const float*)d_in[13];
    const float* bias2 = (const float*)d_in[14];
    const float* lin_w = (const float*)d_in[15];
    const float* lin_b = (const float*)d_in[16];
    float* out = (float*)d_out;

    const int N = in_sizes[0] / 64;
    const int E = in_sizes[1] / 2;
    const int G = out_size / 32;
    const int* src = ei;
    const int* dst = ei + E;

    // ---- workspace carve-up (256B-aligned) ----
    char*  ws  = (char*)d_ws;
    size_t off = 0;
    auto alloc = [&](size_t bytes) -> void* {
        void* p = ws + off;
        off += bytes;
        off = (off + 255) & ~(size_t)255;
        return p;
    };
    float* xl      = (float*)alloc((size_t)N * 64 * sizeof(float));
    float* xr      = (float*)alloc((size_t)N * 64 * sizeof(float));
    float* h1      = (float*)alloc((size_t)N * 64 * sizeof(float));  // also h2
    // zeroed region (contiguous): cnt, novf, sums, cnts
    int*   cnt     = (int*)alloc((size_t)N * sizeof(int));
    int*   novf    = (int*)alloc(256);
    float* sums    = (float*)alloc((size_t)G * 64 * sizeof(float));
    float* cnts    = (float*)alloc((size_t)G * sizeof(float));
    char*  zend    = ws + off;
    int*   ell     = (int*)alloc((size_t)N * ELLC * sizeof(int));
    int*   ovf_dst = (int*)alloc((size_t)OVF_CAP * sizeof(int));
    int*   ovf_src = (int*)alloc((size_t)OVF_CAP * sizeof(int));

    (void)hipMemsetAsync(cnt, 0, (size_t)(zend - (char*)cnt), stream);

    int ggrid  = (N + GROWS - 1) / GROWS;
    int agrid  = (N + 3) / 4;                    // 4 waves/block, 1 wave/dst
    int nchunk = (E + ECHUNK - 1) / ECHUNK;
    int fb     = nchunk * 8;                     // fill blocks (multiple of 8)
    int psize  = (N + 7) / 8;                    // dst partition size

    // ---- fused: XCD-partitioned ELL fill + layer-1 dual GEMM ----
    fill_gemm_kernel<<<fb + ggrid, 256, 0, stream>>>(
        src, dst, cnt, ell, novf, ovf_dst, ovf_src, E, N, psize, fb,
        x, Wl1, bl1, Wr1, br1, xl, xr);

    gat_aggregate_kernel<<<agrid, 256, 0, stream>>>(
        xl, xr, cnt, ell, novf, ovf_dst, ovf_src, att1, bias1, h1, N);

    // ---- layer 2 (h2 aliases h1: gemm2 consumes h1, agg2 overwrites it) ----
    dual_gemm64_kernel<<<ggrid, 256, 0, stream>>>(h1, Wl2, bl2, Wr2, br2, xl, xr, N);
    gat_aggregate_kernel<<<agrid, 256, 0, stream>>>(
        xl, xr, cnt, ell, novf, ovf_dst, ovf_src, att2, bias2, h1, N);

    // ---- pool + final linear ----
    const int NWAVES = 1024;
    pool_kernel<<<256, 256, 0, stream>>>(h1, batch, sums, cnts, N, NWAVES);
    int total = G * 32;
    final_kernel<<<(total + 255) / 256, 256, 0, stream>>>(sums, cnts, lin_w, lin_b, out, total);
}